// Round 10
// baseline (412.138 us; speedup 1.0000x reference)
//
#include <hip/hip_runtime.h>
#include <hip/hip_fp16.h>
#include <math.h>

// GAT 2-layer, N=50000, E=800000 (+N self loops), IN=128, HID=32, HEADS=4, OUT=32
#define NN   50000
#define EE   800000
#define ETOT 850000          // EE + NN
#define NEG  0.2f

// -------- workspace layout (element offsets, 4B units; ints/halfs alias floats) --------
// zero-initialized region (one contiguous memset):
#define O_DEG    0           //    50,000  in-degree per node (int, EXCLUDING self-loop)
#define O_EASUM  50000       //         4  edge_attr sum (scalar)
#define ZERO_ELEMS 50004
// non-zeroed:
#define O_COEF   50004       //         8  coef1[4], coef2 at [4]
#define O_ROWPTR 50012       //    50,001  CSR row pointers (int)
#define O_RANK   100016      //   800,000  rank of edge within its dst row (int)
#define O_CSRSRC 900016      //   850,000  src node per CSR slot (int)
#define O_EASLOT 1750016     //   850,000  edge attr in CSR slot order (float)
#define O_ASRC1  2600016     //   200,000  per-node src logits layer1 [N][4]
#define O_ADST1  2800016     //   200,000  per-node dst logits layer1 [N][4]
#define O_XLH    3000016     // 3,200,000  layer-1 features fp16 [N][128] (6.4M halfs)
#define O_HLH    6200016     //   800,000  layer-2 features fp16 [N][32] (1.6M halfs)
#define O_ASRC2  7000016     //    50,000  per-node src logits layer2
#define O_ADST2  7050016     //    50,000  per-node dst logits layer2
#define WS_ELEMS 7100016     // ~28.4 MB

// -------------------- edge_attr sum + degree count + rank (atomic return is the rank) ---
__global__ __launch_bounds__(256) void k_ea_count(
    const float* __restrict__ ea, const int* __restrict__ ei,
    float* __restrict__ easum, int* __restrict__ deg, int* __restrict__ rank) {
  __shared__ float red[4];
  int e = blockIdx.x * 256 + threadIdx.x;
  float s = 0.f;
  if (e < EE) {
    s = ea[e];
    rank[e] = atomicAdd(deg + ei[EE + e], 1);   // old value = rank within dst row
  }
  #pragma unroll
  for (int o = 32; o > 0; o >>= 1) s += __shfl_down(s, o, 64);
  if ((threadIdx.x & 63) == 0) red[threadIdx.x >> 6] = s;
  __syncthreads();
  if (threadIdx.x == 0) atomicAdd(easum, red[0] + red[1] + red[2] + red[3]);
}

// -------------------- single-dispatch scan (1 block, coalesced chunks) ------------------
// exclusive scan of (deg+1) -> rowptr; deterministic self-loop at last slot of each row;
// coef piggybacked on threads 0..127.
__device__ __forceinline__ int wave_incl_scan(int v, int lane) {
  #pragma unroll
  for (int o = 1; o < 64; o <<= 1) {
    int u = __shfl_up(v, o, 64);
    if (lane >= o) v += u;
  }
  return v;
}

#define SCAN_IT 49   // 49*1024 = 50176 >= NN
__global__ __launch_bounds__(1024) void k_scan_one(
    const int* __restrict__ deg, const float* __restrict__ easum,
    int* __restrict__ rowptr, int* __restrict__ csr_src, float* __restrict__ ea_slot,
    const float* __restrict__ lew1, const float* __restrict__ ae1,
    const float* __restrict__ lew2, const float* __restrict__ ae2,
    float* __restrict__ coef) {
  __shared__ int wsum[16];
  const int t = threadIdx.x;
  const int lane = t & 63, wv = t >> 6;
  if (t < 128) {      // coef: coef1[h] = sum_c lew1[h*32+c]*ae1[h*32+c]; coef2 at [4]
    float p = lew1[t] * ae1[t];
    #pragma unroll
    for (int o = 16; o > 0; o >>= 1) p += __shfl_down(p, o, 32);
    if ((t & 31) == 0) coef[t >> 5] = p;
    if (t < 32) {
      float q = lew2[t] * ae2[t];
      #pragma unroll
      for (int o = 16; o > 0; o >>= 1) q += __shfl_down(q, o, 32);
      if (t == 0) coef[4] = q;
    }
  }
  const float eamean = easum[0] * (1.f / EE);
  int carry = 0;
  int idx = t;
  int v = (idx < NN) ? deg[idx] + 1 : 0;          // +1 = self-loop
  for (int i = 0; i < SCAN_IT; ++i) {
    int nidx = idx + 1024;
    int nv = (i + 1 < SCAN_IT && nidx < NN) ? deg[nidx] + 1 : 0;  // prefetch next chunk
    int incl = wave_incl_scan(v, lane);
    if (lane == 63) wsum[wv] = incl;
    __syncthreads();
    int off = 0, tot = 0;
    #pragma unroll
    for (int k = 0; k < 16; ++k) { int w = wsum[k]; tot += w; if (k < wv) off += w; }
    __syncthreads();                               // wsum consumed before next chunk
    if (idx < NN) {
      int excl = carry + off + incl - v;
      rowptr[idx] = excl;
      int slot = excl + (v - 1);                   // last slot of row = self-loop
      csr_src[slot] = idx;
      ea_slot[slot] = eamean;
    }
    carry += tot;                                  // uniform across all threads
    idx = nidx; v = nv;
  }
  if (t == 0) rowptr[NN] = ETOT;
}

// 32 FMAs against one uniform W row of 32 floats
#define GEMM_STEP(WB, K, XS) {                                              \
    const float4* Wr = (const float4*)((WB) + (size_t)(K));                 \
    _Pragma("unroll")                                                       \
    for (int j4 = 0; j4 < 8; ++j4) {                                        \
      float4 wv = Wr[j4];                                                   \
      acc[j4 * 4 + 0] += (XS) * wv.x;                                       \
      acc[j4 * 4 + 1] += (XS) * wv.y;                                       \
      acc[j4 * 4 + 2] += (XS) * wv.z;                                       \
      acc[j4 * 4 + 3] += (XS) * wv.w;                                       \
    } }

// -------------------- FUSED & INTERLEAVED: layer-1 GEMM  ∥  atomic-free CSR fill --------
// grid = 5*L1_GRID blocks of 64; bid%5==0 -> lin1 (VALU-bound), else fill (latency-bound).
// Interleaving keeps the co-resident mix ~1:4 for the whole kernel -> true overlap
// (R9 ordered the roles back-to-back and got sum, not max).
#define L1_NB ((NN + 63) / 64)      // 782 node-blocks per head
#define LIN1B (L1_NB * 4)           // 3128
__global__ __launch_bounds__(64) void k_fused(
    const float* __restrict__ x, const float* __restrict__ W,
    const float* __restrict__ att_src, const float* __restrict__ att_dst,
    __half* __restrict__ xlh, float* __restrict__ asrc, float* __restrict__ adst,
    const int* __restrict__ ei, const float* __restrict__ eattr,
    const int* __restrict__ rank, const int* __restrict__ rowptr,
    int* __restrict__ csr_src, float* __restrict__ ea_slot) {
  const int g = blockIdx.x / 5;
  const int r = blockIdx.x % 5;
  if (r != 0) {                               // ---- fill path (no atomics) ----
    int e = (g * 4 + r - 1) * 64 + threadIdx.x;
    if (e < EE) {
      int s = ei[e];
      int d = ei[EE + e];
      float ea = eattr[e];
      int slot = rowptr[d] + rank[e];
      csr_src[slot] = s;
      ea_slot[slot] = ea;
    }
    return;
  }
  // ---- lin1 path ----
  const int h   = g / L1_NB;                  // head (uniform)
  const int n   = (g % L1_NB) * 64 + threadIdx.x;
  const int nc  = n < NN ? n : NN - 1;
  const float4* xr = (const float4*)(x + (size_t)nc * 128);
  const float*  Wh = W + h * 32;              // uniform base
  float acc[32];
  #pragma unroll
  for (int j = 0; j < 32; ++j) acc[j] = 0.f;
  float4 xv = xr[0];
  for (int kt = 0; kt < 32; ++kt) {
    float4 cur = xv;
    if (kt < 31) xv = xr[kt + 1];             // prefetch next 16B of x
    GEMM_STEP(Wh, (kt * 4 + 0) * 128, cur.x);
    GEMM_STEP(Wh, (kt * 4 + 1) * 128, cur.y);
    GEMM_STEP(Wh, (kt * 4 + 2) * 128, cur.z);
    GEMM_STEP(Wh, (kt * 4 + 3) * 128, cur.w);
  }
  if (n < NN) {
    __align__(16) __half hbuf[32];
    #pragma unroll
    for (int j = 0; j < 32; ++j) hbuf[j] = __float2half_rn(acc[j]);
    float4* dst = (float4*)(xlh + (size_t)n * 128 + h * 32);   // 64 B, 16B-aligned
    #pragma unroll
    for (int i = 0; i < 4; ++i) dst[i] = ((const float4*)hbuf)[i];
    float ss = 0.f, sd = 0.f;
    #pragma unroll
    for (int j = 0; j < 32; ++j) {
      ss += acc[j] * att_src[h * 32 + j];     // uniform
      sd += acc[j] * att_dst[h * 32 + j];
    }
    asrc[n * 4 + h] = ss;
    adst[n * 4 + h] = sd;
  }
}

// -------------------- FUSED: layer-1 aggregation -> ELU -> layer-2 GEMM -----------------
// Phase A: agg1 (batch-4 pipelined), result+bias1+ELU into LDS (no out1 round-trip).
// Phase B: lin2 from LDS, 32 threads/node: thread j = output channel j.
// 6250 blocks x 8 nodes = exactly NN (no tail).
__global__ __launch_bounds__(256) void k_agg1lin2(
    const int* __restrict__ rowptr, const int* __restrict__ csr_src,
    const float* __restrict__ ea_slot, const float* __restrict__ asrc,
    const float* __restrict__ adst, const float* __restrict__ coef,
    const __half* __restrict__ xlh, const float* __restrict__ bias1,
    const float* __restrict__ W2,
    const float* __restrict__ as2w, const float* __restrict__ ad2w,
    __half* __restrict__ hlh, float* __restrict__ asrc2, float* __restrict__ adst2) {
  __shared__ float hsh[8][128];               // 4 KB
  const int ni = threadIdx.x >> 5;            // node within block
  const int n = blockIdx.x * 8 + ni;          // exact coverage, no tail
  const int l = threadIdx.x & 31;
  const int c4 = l << 2;                      // 4 channels per lane
  const int h = l >> 3;                       // head of this channel group
  float cf = coef[h];
  float ad = adst[(size_t)n * 4 + h];
  int r0 = rowptr[n], r1 = rowptr[n + 1];     // r1 > r0 (self-loop)
  float a0 = 0.f, a1 = 0.f, a2 = 0.f, a3 = 0.f, den = 0.f;
  for (int j = r0; j < r1; j += 4) {
    int sv[4]; float eav[4], asv[4]; uint2 raw[4];
    #pragma unroll
    for (int k = 0; k < 4; ++k) {
      int jj = (j + k < r1) ? (j + k) : (r1 - 1);
      sv[k] = csr_src[jj];
      eav[k] = ea_slot[jj];
    }
    #pragma unroll
    for (int k = 0; k < 4; ++k) {
      asv[k] = asrc[(size_t)sv[k] * 4 + h];
      raw[k] = *(const uint2*)(xlh + (size_t)sv[k] * 128 + c4);   // 4 halfs
    }
    #pragma unroll
    for (int k = 0; k < 4; ++k) {
      float alpha = asv[k] + ad + eav[k] * cf;
      alpha = alpha > 0.f ? alpha : NEG * alpha;
      float ex = (j + k < r1) ? __expf(alpha) : 0.f;   // tail mask
      __half2 p0, p1;
      *(unsigned int*)&p0 = raw[k].x;
      *(unsigned int*)&p1 = raw[k].y;
      float2 f0 = __half22float2(p0), f1 = __half22float2(p1);
      a0 += ex * f0.x;
      a1 += ex * f0.y;
      a2 += ex * f1.x;
      a3 += ex * f1.y;
      den += ex;
    }
  }
  float inv = 1.f / den;
  float4 b1 = *(const float4*)(bias1 + c4);
  float v0 = a0 * inv + b1.x;  v0 = v0 > 0.f ? v0 : (__expf(v0) - 1.f);  // ELU
  float v1 = a1 * inv + b1.y;  v1 = v1 > 0.f ? v1 : (__expf(v1) - 1.f);
  float v2 = a2 * inv + b1.z;  v2 = v2 > 0.f ? v2 : (__expf(v2) - 1.f);
  float v3 = a3 * inv + b1.w;  v3 = v3 > 0.f ? v3 : (__expf(v3) - 1.f);
  hsh[ni][c4 + 0] = v0;
  hsh[ni][c4 + 1] = v1;
  hsh[ni][c4 + 2] = v2;
  hsh[ni][c4 + 3] = v3;
  __syncthreads();
  // ---- lin2: thread (ni, l) computes output channel l of node n ----
  const float* hrow = hsh[ni];
  float acc2 = 0.f;
  #pragma unroll
  for (int k4 = 0; k4 < 32; ++k4) {
    float4 hv = *(const float4*)(hrow + k4 * 4);        // LDS broadcast within node
    acc2 += hv.x * W2[(k4 * 4 + 0) * 32 + l];           // coalesced, L1-resident
    acc2 += hv.y * W2[(k4 * 4 + 1) * 32 + l];
    acc2 += hv.z * W2[(k4 * 4 + 2) * 32 + l];
    acc2 += hv.w * W2[(k4 * 4 + 3) * 32 + l];
  }
  hlh[(size_t)n * 32 + l] = __float2half_rn(acc2);
  float p = acc2 * as2w[l];
  float q = acc2 * ad2w[l];
  #pragma unroll
  for (int o = 16; o > 0; o >>= 1) {
    p += __shfl_down(p, o, 32);
    q += __shfl_down(q, o, 32);
  }
  if (l == 0) {
    asrc2[n] = p;
    adst2[n] = q;
  }
}

// -------------------- layer-2 aggregation (fused softmax), batch-4 pipelined ------------
__global__ __launch_bounds__(256) void k_agg2(
    const int* __restrict__ rowptr, const int* __restrict__ csr_src,
    const float* __restrict__ ea_slot, const float* __restrict__ asrc2,
    const float* __restrict__ adst2, const float* __restrict__ coef,
    const __half* __restrict__ hlh, const float* __restrict__ bias2,
    float* __restrict__ out) {
  int n = blockIdx.x * 32 + (threadIdx.x >> 3);
  if (n >= NN) return;
  int c4 = (threadIdx.x & 7) << 2;
  float cf = coef[4];
  float ad = adst2[n];
  int r0 = rowptr[n], r1 = rowptr[n + 1];
  float a0 = 0.f, a1 = 0.f, a2 = 0.f, a3 = 0.f, den = 0.f;
  for (int j = r0; j < r1; j += 4) {
    int sv[4]; float eav[4], asv[4]; uint2 raw[4];
    #pragma unroll
    for (int k = 0; k < 4; ++k) {
      int jj = (j + k < r1) ? (j + k) : (r1 - 1);
      sv[k] = csr_src[jj];
      eav[k] = ea_slot[jj];
    }
    #pragma unroll
    for (int k = 0; k < 4; ++k) {
      asv[k] = asrc2[sv[k]];
      raw[k] = *(const uint2*)(hlh + (size_t)sv[k] * 32 + c4);   // 4 halfs
    }
    #pragma unroll
    for (int k = 0; k < 4; ++k) {
      float alpha = asv[k] + ad + eav[k] * cf;
      alpha = alpha > 0.f ? alpha : NEG * alpha;
      float ex = (j + k < r1) ? __expf(alpha) : 0.f;   // tail mask
      __half2 p0, p1;
      *(unsigned int*)&p0 = raw[k].x;
      *(unsigned int*)&p1 = raw[k].y;
      float2 f0 = __half22float2(p0), f1 = __half22float2(p1);
      a0 += ex * f0.x;
      a1 += ex * f0.y;
      a2 += ex * f1.x;
      a3 += ex * f1.y;
      den += ex;
    }
  }
  float inv = 1.f / den;
  float4 b = *(const float4*)(bias2 + c4);
  *(float4*)(out + (size_t)n * 32 + c4) =
      make_float4(a0 * inv + b.x, a1 * inv + b.y, a2 * inv + b.z, a3 * inv + b.w);
}

extern "C" void kernel_launch(void* const* d_in, const int* in_sizes, int n_in,
                              void* d_out, int out_size, void* d_ws, size_t ws_size,
                              hipStream_t stream) {
  const float* x        = (const float*)d_in[0];
  const int*   ei       = (const int*)d_in[1];
  const float* eattr    = (const float*)d_in[2];
  const float* lin1_w   = (const float*)d_in[3];
  const float* att1_src = (const float*)d_in[4];
  const float* att1_dst = (const float*)d_in[5];
  const float* lin1_ew  = (const float*)d_in[6];
  const float* att1_e   = (const float*)d_in[7];
  const float* bias1    = (const float*)d_in[8];
  const float* lin2_w   = (const float*)d_in[9];
  const float* att2_src = (const float*)d_in[10];
  const float* att2_dst = (const float*)d_in[11];
  const float* lin2_ew  = (const float*)d_in[12];
  const float* att2_e   = (const float*)d_in[13];
  const float* bias2    = (const float*)d_in[14];
  float* out = (float*)d_out;
  float* ws  = (float*)d_ws;
  int*   wsi = (int*)d_ws;

  int*    deg     = wsi + O_DEG;
  float*  easum   = ws + O_EASUM;
  float*  coef    = ws + O_COEF;
  int*    rowptr  = wsi + O_ROWPTR;
  int*    rank    = wsi + O_RANK;
  int*    csr_src = wsi + O_CSRSRC;
  float*  ea_slot = ws + O_EASLOT;
  float*  asrc1   = ws + O_ASRC1;
  float*  adst1   = ws + O_ADST1;
  __half* xlh     = (__half*)(ws + O_XLH);
  __half* hlh     = (__half*)(ws + O_HLH);
  float*  asrc2   = ws + O_ASRC2;
  float*  adst2   = ws + O_ADST2;

  // zero deg/easum (ws poisoned 0xAA each call)
  hipMemsetAsync(ws, 0, (size_t)ZERO_ELEMS * sizeof(float), stream);

  // degree + rank + edge-attr sum (1 thread/edge; atomic return value = rank)
  k_ea_count<<<(EE + 255) / 256, 256, 0, stream>>>(eattr, ei, easum, deg, rank);

  // single-dispatch scan (+ self-loop slots + coef)
  k_scan_one<<<1, 1024, 0, stream>>>(deg, easum, rowptr, csr_src, ea_slot,
                                     lin1_ew, att1_e, lin2_ew, att2_e, coef);

  // layer-1 GEMM interleaved 1:4 with atomic-free CSR fill
  k_fused<<<LIN1B * 5, 64, 0, stream>>>(x, lin1_w, att1_src, att1_dst, xlh, asrc1, adst1,
                                        ei, eattr, rank, rowptr, csr_src, ea_slot);

  // layer-1 aggregation + ELU + layer-2 GEMM (LDS handoff, no out1 round-trip)
  k_agg1lin2<<<NN / 8, 256, 0, stream>>>(rowptr, csr_src, ea_slot, asrc1, adst1, coef,
                                         xlh, bias1, lin2_w, att2_src, att2_dst,
                                         hlh, asrc2, adst2);

  // layer-2 aggregation
  k_agg2<<<(NN + 31) / 32, 256, 0, stream>>>(rowptr, csr_src, ea_slot, asrc2, adst2, coef,
                                             hlh, bias2, out);
}

// Round 11
// 403.151 us; speedup vs baseline: 1.0223x; 1.0223x over previous
//
#include <hip/hip_runtime.h>
#include <hip/hip_fp16.h>
#include <math.h>

// GAT 2-layer, N=50000, E=800000 (+N self loops), IN=128, HID=32, HEADS=4, OUT=32
#define NN   50000
#define EE   800000
#define ETOT 850000          // EE + NN
#define NEG  0.2f
#define EA_BLOCKS ((EE + 255) / 256)   // 3125

// -------- workspace layout (element offsets, 4B units; ints/halfs alias floats) --------
// zero-initialized region (one contiguous memset):
#define O_DEG    0           //    50,000  in-degree per node (int, EXCLUDING self-loop)
#define ZERO_ELEMS 50000
// non-zeroed:
#define O_EAPART 50000       //     3,128  per-block edge-attr partial sums (float)
#define O_COEF   53128       //         8  coef1[4], coef2 at [4]
#define O_ROWPTR 53136       //    50,008  CSR row pointers (int)
#define O_RANK   103144      //   800,000  rank of edge within its dst row (int)
#define O_CSRSRC 903144      //   850,000  src node per CSR slot (int)
#define O_EASLOT 1753144     //   850,000  edge attr in CSR slot order (float)
#define O_ASRC1  2603144     //   200,000  per-node src logits layer1 [N][4]
#define O_ADST1  2803144     //   200,000  per-node dst logits layer1 [N][4]
#define O_XLH    3003144     // 3,200,000  layer-1 features fp16 [N][128] (6.4M halfs)
#define O_OUT1   6203144     // 6,400,000  layer-1 agg output fp32 [N][128]
#define O_HLH    12603144    //   800,000  layer-2 features fp16 [N][32] (1.6M halfs)
#define O_ASRC2  13403144    //    50,000  per-node src logits layer2
#define O_ADST2  13453144    //    50,000  per-node dst logits layer2
#define WS_ELEMS 13503144    // ~54 MB

// ---------- degree count + rank (atomic return = rank) + PER-BLOCK ea partial ----------
// NO same-address atomics: each block stores its partial with a plain store
// (R8/R10 regression root-cause: 3125 serialized atomicAdds on one easum address).
__global__ __launch_bounds__(256) void k_ea_count(
    const float* __restrict__ ea, const int* __restrict__ ei,
    float* __restrict__ eapart, int* __restrict__ deg, int* __restrict__ rank) {
  __shared__ float red[4];
  int e = blockIdx.x * 256 + threadIdx.x;
  float s = 0.f;
  if (e < EE) {
    s = ea[e];
    rank[e] = atomicAdd(deg + ei[EE + e], 1);   // old value = rank within dst row
  }
  #pragma unroll
  for (int o = 32; o > 0; o >>= 1) s += __shfl_down(s, o, 64);
  if ((threadIdx.x & 63) == 0) red[threadIdx.x >> 6] = s;
  __syncthreads();
  if (threadIdx.x == 0) eapart[blockIdx.x] = red[0] + red[1] + red[2] + red[3];
}

// -------------------- single-dispatch scan (1 block, coalesced chunks) ------------------
// reduces eapart -> eamean; coef; exclusive scan of (deg+1) -> rowptr;
// deterministic self-loop written at last slot of each row.
__device__ __forceinline__ int wave_incl_scan(int v, int lane) {
  #pragma unroll
  for (int o = 1; o < 64; o <<= 1) {
    int u = __shfl_up(v, o, 64);
    if (lane >= o) v += u;
  }
  return v;
}

#define SCAN_IT 49   // 49*1024 = 50176 >= NN
__global__ __launch_bounds__(1024) void k_scan_one(
    const int* __restrict__ deg, const float* __restrict__ eapart,
    int* __restrict__ rowptr, int* __restrict__ csr_src, float* __restrict__ ea_slot,
    const float* __restrict__ lew1, const float* __restrict__ ae1,
    const float* __restrict__ lew2, const float* __restrict__ ae2,
    float* __restrict__ coef) {
  __shared__ int wsum[16];
  __shared__ float fsum[16];
  __shared__ float s_eamean;
  const int t = threadIdx.x;
  const int lane = t & 63, wv = t >> 6;
  // ---- reduce eapart (3125 partials) ----
  float fs = 0.f;
  #pragma unroll
  for (int i = 0; i < 4; ++i) {
    int idx = t + i * 1024;
    if (idx < EA_BLOCKS) fs += eapart[idx];
  }
  #pragma unroll
  for (int o = 32; o > 0; o >>= 1) fs += __shfl_down(fs, o, 64);
  if (lane == 0) fsum[wv] = fs;
  __syncthreads();
  if (t == 0) {
    float tot = 0.f;
    #pragma unroll
    for (int k = 0; k < 16; ++k) tot += fsum[k];
    s_eamean = tot * (1.f / EE);
  }
  // ---- coef (threads 0..127) ----
  if (t < 128) {
    float p = lew1[t] * ae1[t];
    #pragma unroll
    for (int o = 16; o > 0; o >>= 1) p += __shfl_down(p, o, 32);
    if ((t & 31) == 0) coef[t >> 5] = p;
    if (t < 32) {
      float q = lew2[t] * ae2[t];
      #pragma unroll
      for (int o = 16; o > 0; o >>= 1) q += __shfl_down(q, o, 32);
      if (t == 0) coef[4] = q;
    }
  }
  __syncthreads();
  const float eamean = s_eamean;
  // ---- chunked coalesced scan ----
  int carry = 0;
  int idx = t;
  int v = (idx < NN) ? deg[idx] + 1 : 0;          // +1 = self-loop
  for (int i = 0; i < SCAN_IT; ++i) {
    int nidx = idx + 1024;
    int nv = (i + 1 < SCAN_IT && nidx < NN) ? deg[nidx] + 1 : 0;  // prefetch next chunk
    int incl = wave_incl_scan(v, lane);
    if (lane == 63) wsum[wv] = incl;
    __syncthreads();
    int off = 0, tot = 0;
    #pragma unroll
    for (int k = 0; k < 16; ++k) { int w = wsum[k]; tot += w; if (k < wv) off += w; }
    __syncthreads();                               // wsum consumed before next chunk
    if (idx < NN) {
      int excl = carry + off + incl - v;
      rowptr[idx] = excl;
      int slot = excl + (v - 1);                   // last slot of row = self-loop
      csr_src[slot] = idx;
      ea_slot[slot] = eamean;
    }
    carry += tot;                                  // uniform across all threads
    idx = nidx; v = nv;
  }
  if (t == 0) rowptr[NN] = ETOT;
}

// 32 FMAs against one uniform W row of 32 floats
#define GEMM_STEP(WB, K, XS) {                                              \
    const float4* Wr = (const float4*)((WB) + (size_t)(K));                 \
    _Pragma("unroll")                                                       \
    for (int j4 = 0; j4 < 8; ++j4) {                                        \
      float4 wv = Wr[j4];                                                   \
      acc[j4 * 4 + 0] += (XS) * wv.x;                                       \
      acc[j4 * 4 + 1] += (XS) * wv.y;                                       \
      acc[j4 * 4 + 2] += (XS) * wv.z;                                       \
      acc[j4 * 4 + 3] += (XS) * wv.w;                                       \
    } }

// -------------------- FUSED & INTERLEAVED: layer-1 GEMM  ∥  atomic-free CSR fill --------
#define L1_NB ((NN + 63) / 64)      // 782 node-blocks per head
#define LIN1B (L1_NB * 4)           // 3128
__global__ __launch_bounds__(64) void k_fused(
    const float* __restrict__ x, const float* __restrict__ W,
    const float* __restrict__ att_src, const float* __restrict__ att_dst,
    __half* __restrict__ xlh, float* __restrict__ asrc, float* __restrict__ adst,
    const int* __restrict__ ei, const float* __restrict__ eattr,
    const int* __restrict__ rank, const int* __restrict__ rowptr,
    int* __restrict__ csr_src, float* __restrict__ ea_slot) {
  const int g = blockIdx.x / 5;
  const int r = blockIdx.x % 5;
  if (r != 0) {                               // ---- fill path (no atomics) ----
    int e = (g * 4 + r - 1) * 64 + threadIdx.x;
    if (e < EE) {
      int s = ei[e];
      int d = ei[EE + e];
      float ea = eattr[e];
      int slot = rowptr[d] + rank[e];
      csr_src[slot] = s;
      ea_slot[slot] = ea;
    }
    return;
  }
  // ---- lin1 path ----
  const int h   = g / L1_NB;                  // head (uniform)
  const int n   = (g % L1_NB) * 64 + threadIdx.x;
  const int nc  = n < NN ? n : NN - 1;
  const float4* xr = (const float4*)(x + (size_t)nc * 128);
  const float*  Wh = W + h * 32;              // uniform base
  float acc[32];
  #pragma unroll
  for (int j = 0; j < 32; ++j) acc[j] = 0.f;
  float4 xv = xr[0];
  for (int kt = 0; kt < 32; ++kt) {
    float4 cur = xv;
    if (kt < 31) xv = xr[kt + 1];             // prefetch next 16B of x
    GEMM_STEP(Wh, (kt * 4 + 0) * 128, cur.x);
    GEMM_STEP(Wh, (kt * 4 + 1) * 128, cur.y);
    GEMM_STEP(Wh, (kt * 4 + 2) * 128, cur.z);
    GEMM_STEP(Wh, (kt * 4 + 3) * 128, cur.w);
  }
  if (n < NN) {
    __align__(16) __half hbuf[32];
    #pragma unroll
    for (int j = 0; j < 32; ++j) hbuf[j] = __float2half_rn(acc[j]);
    float4* dst = (float4*)(xlh + (size_t)n * 128 + h * 32);   // 64 B, 16B-aligned
    #pragma unroll
    for (int i = 0; i < 4; ++i) dst[i] = ((const float4*)hbuf)[i];
    float ss = 0.f, sd = 0.f;
    #pragma unroll
    for (int j = 0; j < 32; ++j) {
      ss += acc[j] * att_src[h * 32 + j];     // uniform
      sd += acc[j] * att_dst[h * 32 + j];
    }
    asrc[n * 4 + h] = ss;
    adst[n * 4 + h] = sd;
  }
}

// -------------------- layer-1 aggregation (fused softmax), batch-4 pipelined ------------
__global__ __launch_bounds__(256) void k_agg1(
    const int* __restrict__ rowptr, const int* __restrict__ csr_src,
    const float* __restrict__ ea_slot, const float* __restrict__ asrc,
    const float* __restrict__ adst, const float* __restrict__ coef,
    const __half* __restrict__ xlh, float* __restrict__ out1) {
  int n = blockIdx.x * 8 + (threadIdx.x >> 5);
  if (n >= NN) return;
  int l = threadIdx.x & 31;
  int c4 = l << 2;                    // 4 channels per lane, 32 lanes = 128 ch
  int h = l >> 3;                     // head of this channel group
  float cf = coef[h];
  float ad = adst[(size_t)n * 4 + h];
  int r0 = rowptr[n], r1 = rowptr[n + 1];   // r1 > r0 (self-loop)
  float a0 = 0.f, a1 = 0.f, a2 = 0.f, a3 = 0.f, den = 0.f;
  for (int j = r0; j < r1; j += 4) {
    int sv[4]; float eav[4], asv[4]; uint2 raw[4];
    #pragma unroll
    for (int k = 0; k < 4; ++k) {
      int jj = (j + k < r1) ? (j + k) : (r1 - 1);
      sv[k] = csr_src[jj];
      eav[k] = ea_slot[jj];
    }
    #pragma unroll
    for (int k = 0; k < 4; ++k) {
      asv[k] = asrc[(size_t)sv[k] * 4 + h];
      raw[k] = *(const uint2*)(xlh + (size_t)sv[k] * 128 + c4);   // 4 halfs
    }
    #pragma unroll
    for (int k = 0; k < 4; ++k) {
      float alpha = asv[k] + ad + eav[k] * cf;
      alpha = alpha > 0.f ? alpha : NEG * alpha;
      float ex = (j + k < r1) ? __expf(alpha) : 0.f;   // tail mask
      __half2 p0, p1;
      *(unsigned int*)&p0 = raw[k].x;
      *(unsigned int*)&p1 = raw[k].y;
      float2 f0 = __half22float2(p0), f1 = __half22float2(p1);
      a0 += ex * f0.x;
      a1 += ex * f0.y;
      a2 += ex * f1.x;
      a3 += ex * f1.y;
      den += ex;
    }
  }
  float inv = 1.f / den;
  *(float4*)(out1 + (size_t)n * 128 + c4) = make_float4(a0 * inv, a1 * inv, a2 * inv, a3 * inv);
}

// -------------------- layer-2 GEMM: hl(fp16) = elu(out1+bias1) @ W2, plus logits --------
__global__ __launch_bounds__(64) void k_lin2(
    const float* __restrict__ out1, const float* __restrict__ bias1,
    const float* __restrict__ W2,
    const float* __restrict__ as2w, const float* __restrict__ ad2w,
    __half* __restrict__ hlh, float* __restrict__ asrc2, float* __restrict__ adst2) {
  const int n  = blockIdx.x * 64 + threadIdx.x;
  const int nc = n < NN ? n : NN - 1;
  const float4* xr = (const float4*)(out1 + (size_t)nc * 128);
  const float4* br = (const float4*)bias1;   // uniform
  float acc[32];
  #pragma unroll
  for (int j = 0; j < 32; ++j) acc[j] = 0.f;
  float4 xv = xr[0];
  for (int kt = 0; kt < 32; ++kt) {
    float4 cur = xv;
    if (kt < 31) xv = xr[kt + 1];
    float4 b = br[kt];                       // uniform
    cur.x += b.x; cur.y += b.y; cur.z += b.z; cur.w += b.w;
    cur.x = cur.x > 0.f ? cur.x : (expf(cur.x) - 1.f);   // ELU (once per element)
    cur.y = cur.y > 0.f ? cur.y : (expf(cur.y) - 1.f);
    cur.z = cur.z > 0.f ? cur.z : (expf(cur.z) - 1.f);
    cur.w = cur.w > 0.f ? cur.w : (expf(cur.w) - 1.f);
    GEMM_STEP(W2, (kt * 4 + 0) * 32, cur.x);
    GEMM_STEP(W2, (kt * 4 + 1) * 32, cur.y);
    GEMM_STEP(W2, (kt * 4 + 2) * 32, cur.z);
    GEMM_STEP(W2, (kt * 4 + 3) * 32, cur.w);
  }
  if (n < NN) {
    __align__(16) __half hbuf[32];
    #pragma unroll
    for (int j = 0; j < 32; ++j) hbuf[j] = __float2half_rn(acc[j]);
    float4* dst = (float4*)(hlh + (size_t)n * 32);   // 64 B
    #pragma unroll
    for (int i = 0; i < 4; ++i) dst[i] = ((const float4*)hbuf)[i];
    float ps = 0.f, pd = 0.f;
    #pragma unroll
    for (int j = 0; j < 32; ++j) {
      ps += acc[j] * as2w[j];                // uniform
      pd += acc[j] * ad2w[j];
    }
    asrc2[n] = ps;
    adst2[n] = pd;
  }
}

// -------------------- layer-2 aggregation (fused softmax), batch-4 pipelined ------------
__global__ __launch_bounds__(256) void k_agg2(
    const int* __restrict__ rowptr, const int* __restrict__ csr_src,
    const float* __restrict__ ea_slot, const float* __restrict__ asrc2,
    const float* __restrict__ adst2, const float* __restrict__ coef,
    const __half* __restrict__ hlh, const float* __restrict__ bias2,
    float* __restrict__ out) {
  int n = blockIdx.x * 32 + (threadIdx.x >> 3);
  if (n >= NN) return;
  int c4 = (threadIdx.x & 7) << 2;
  float cf = coef[4];
  float ad = adst2[n];
  int r0 = rowptr[n], r1 = rowptr[n + 1];
  float a0 = 0.f, a1 = 0.f, a2 = 0.f, a3 = 0.f, den = 0.f;
  for (int j = r0; j < r1; j += 4) {
    int sv[4]; float eav[4], asv[4]; uint2 raw[4];
    #pragma unroll
    for (int k = 0; k < 4; ++k) {
      int jj = (j + k < r1) ? (j + k) : (r1 - 1);
      sv[k] = csr_src[jj];
      eav[k] = ea_slot[jj];
    }
    #pragma unroll
    for (int k = 0; k < 4; ++k) {
      asv[k] = asrc2[sv[k]];
      raw[k] = *(const uint2*)(hlh + (size_t)sv[k] * 32 + c4);   // 4 halfs
    }
    #pragma unroll
    for (int k = 0; k < 4; ++k) {
      float alpha = asv[k] + ad + eav[k] * cf;
      alpha = alpha > 0.f ? alpha : NEG * alpha;
      float ex = (j + k < r1) ? __expf(alpha) : 0.f;   // tail mask
      __half2 p0, p1;
      *(unsigned int*)&p0 = raw[k].x;
      *(unsigned int*)&p1 = raw[k].y;
      float2 f0 = __half22float2(p0), f1 = __half22float2(p1);
      a0 += ex * f0.x;
      a1 += ex * f0.y;
      a2 += ex * f1.x;
      a3 += ex * f1.y;
      den += ex;
    }
  }
  float inv = 1.f / den;
  float4 b = *(const float4*)(bias2 + c4);
  *(float4*)(out + (size_t)n * 32 + c4) =
      make_float4(a0 * inv + b.x, a1 * inv + b.y, a2 * inv + b.z, a3 * inv + b.w);
}

extern "C" void kernel_launch(void* const* d_in, const int* in_sizes, int n_in,
                              void* d_out, int out_size, void* d_ws, size_t ws_size,
                              hipStream_t stream) {
  const float* x        = (const float*)d_in[0];
  const int*   ei       = (const int*)d_in[1];
  const float* eattr    = (const float*)d_in[2];
  const float* lin1_w   = (const float*)d_in[3];
  const float* att1_src = (const float*)d_in[4];
  const float* att1_dst = (const float*)d_in[5];
  const float* lin1_ew  = (const float*)d_in[6];
  const float* att1_e   = (const float*)d_in[7];
  const float* bias1    = (const float*)d_in[8];
  const float* lin2_w   = (const float*)d_in[9];
  const float* att2_src = (const float*)d_in[10];
  const float* att2_dst = (const float*)d_in[11];
  const float* lin2_ew  = (const float*)d_in[12];
  const float* att2_e   = (const float*)d_in[13];
  const float* bias2    = (const float*)d_in[14];
  float* out = (float*)d_out;
  float* ws  = (float*)d_ws;
  int*   wsi = (int*)d_ws;

  int*    deg     = wsi + O_DEG;
  float*  eapart  = ws + O_EAPART;
  float*  coef    = ws + O_COEF;
  int*    rowptr  = wsi + O_ROWPTR;
  int*    rank    = wsi + O_RANK;
  int*    csr_src = wsi + O_CSRSRC;
  float*  ea_slot = ws + O_EASLOT;
  float*  asrc1   = ws + O_ASRC1;
  float*  adst1   = ws + O_ADST1;
  __half* xlh     = (__half*)(ws + O_XLH);
  float*  out1    = ws + O_OUT1;
  __half* hlh     = (__half*)(ws + O_HLH);
  float*  asrc2   = ws + O_ASRC2;
  float*  adst2   = ws + O_ADST2;

  // zero deg (ws poisoned 0xAA each call)
  hipMemsetAsync(ws, 0, (size_t)ZERO_ELEMS * sizeof(float), stream);

  // degree + rank + per-block ea partials (plain stores; no same-address atomics)
  k_ea_count<<<EA_BLOCKS, 256, 0, stream>>>(eattr, ei, eapart, deg, rank);

  // single-dispatch: eamean reduce + coef + scan + self-loop slots
  k_scan_one<<<1, 1024, 0, stream>>>(deg, eapart, rowptr, csr_src, ea_slot,
                                     lin1_ew, att1_e, lin2_ew, att2_e, coef);

  // layer-1 GEMM interleaved 1:4 with atomic-free CSR fill
  k_fused<<<LIN1B * 5, 64, 0, stream>>>(x, lin1_w, att1_src, att1_dst, xlh, asrc1, adst1,
                                        ei, eattr, rank, rowptr, csr_src, ea_slot);

  // layer-1 aggregation (fused softmax)
  k_agg1<<<(NN + 7) / 8, 256, 0, stream>>>(rowptr, csr_src, ea_slot, asrc1, adst1, coef,
                                           xlh, out1);

  // layer-2 GEMM
  k_lin2<<<(NN + 63) / 64, 64, 0, stream>>>(out1, bias1, lin2_w, att2_src, att2_dst,
                                            hlh, asrc2, adst2);

  // layer-2 aggregation
  k_agg2<<<(NN + 31) / 32, 256, 0, stream>>>(rowptr, csr_src, ea_slot, asrc2, adst2, coef,
                                             hlh, bias2, out);
}